// Round 6
// baseline (453.260 us; speedup 1.0000x reference)
//
#include <hip/hip_runtime.h>
#include <cfloat>
#include <math.h>

// Problem constants (z: [16,64,64,256] fp32, codebook: [1024,256] fp32)
#define P_TOT 65536
#define DIM   256
#define KTOT  1024
#define BETA_ 0.25f
#define EPS_  1e-5f
// flag threshold: >= 2*(2*delta_ze) + 2*ULP(dist) with worst-case
// delta_ze <= ~8e-6 (3-term bf16 split + ref fp32 err) and ULP <= 3.05e-5.
#define MARGIN_ 1.5e-4f

// d_out layout (float32, concatenated in reference return order):
// [0, P*D) z_q_st | [P*D+0..3] losses+perplexity | [P*D+4, +P) indices
// vq_pre temporarily stores zh/zl bf16 (512B+512B per row) in the z_q_st
// region; each argmin block consumes only its own 128 rows before
// overwriting them with the real z_q_st (flagged rows finished by vq_fix).
#define OUT_LOSS_OFF ((size_t)P_TOT * DIM)
#define OUT_IDX_OFF  (OUT_LOSS_OFF + 4)

typedef __attribute__((ext_vector_type(8))) short s16x8;   // 8 bf16 (4 VGPRs)
typedef __attribute__((ext_vector_type(4))) float f32x4;   // MFMA acc

__device__ __forceinline__ unsigned short f2bf(float x) {  // RNE f32->bf16
    unsigned u = __float_as_uint(x);
    u += 0x7FFFu + ((u >> 16) & 1u);
    return (unsigned short)(u >> 16);
}
__device__ __forceinline__ float bf2f(unsigned short h) {
    return __uint_as_float(((unsigned)h) << 16);
}
// async global->LDS direct copy, 16B per lane; lds ptr MUST be wave-uniform.
__device__ __forceinline__ void gl16(const void* g, void* l) {
    __builtin_amdgcn_global_load_lds(
        (const __attribute__((address_space(1))) unsigned int*)g,
        (__attribute__((address_space(3))) unsigned int*)l, 16, 0, 0);
}

// ------- fused pre-pass: zsplit (blocks < P/4) + codebook prep (rest) -------
// z part:  z2[p] = sum(z[p]^2); out row p: [512B zh | 512B zl]
// cb part: e2[k]; cbi row k: [512B cbh | 512B cbl]; zero hist/loss/flags
__global__ __launch_bounds__(256) void vq_pre(
    const float* __restrict__ z, const float* __restrict__ cb,
    float* __restrict__ z2, float* __restrict__ e2,
    char* __restrict__ cbi, unsigned int* __restrict__ hist,
    float* __restrict__ loss_sum, unsigned int* __restrict__ flag_cnt,
    float* __restrict__ out)
{
    const int tid = threadIdx.x;
    const int lane = tid & 63;
    const int wave = tid >> 6;
    const int bid = blockIdx.x;

    if (bid < P_TOT / 4) {
        const int p = bid * 4 + wave;
        float4 v = *(const float4*)(z + (size_t)p * DIM + lane * 4);
        float s = v.x * v.x + v.y * v.y + v.z * v.z + v.w * v.w;
        #pragma unroll
        for (int off = 32; off > 0; off >>= 1) s += __shfl_down(s, off, 64);
        if (lane == 0) z2[p] = s;

        unsigned short h0 = f2bf(v.x), h1 = f2bf(v.y), h2 = f2bf(v.z), h3 = f2bf(v.w);
        unsigned short l0 = f2bf(v.x - bf2f(h0)), l1 = f2bf(v.y - bf2f(h1));
        unsigned short l2 = f2bf(v.z - bf2f(h2)), l3 = f2bf(v.w - bf2f(h3));
        uint2 hp, lp;
        hp.x = (unsigned)h0 | ((unsigned)h1 << 16); hp.y = (unsigned)h2 | ((unsigned)h3 << 16);
        lp.x = (unsigned)l0 | ((unsigned)l1 << 16); lp.y = (unsigned)l2 | ((unsigned)l3 << 16);
        char* rowb = (char*)out + (size_t)p * 1024;
        *(uint2*)(rowb + lane * 8) = hp;
        *(uint2*)(rowb + 512 + lane * 8) = lp;
    } else {
        const int rel = bid - P_TOT / 4;
        const int k = rel * 4 + wave;
        float4 v = *(const float4*)(cb + (size_t)k * DIM + lane * 4);
        float s = v.x * v.x + v.y * v.y + v.z * v.z + v.w * v.w;
        #pragma unroll
        for (int off = 32; off > 0; off >>= 1) s += __shfl_down(s, off, 64);
        if (lane == 0) e2[k] = s;

        unsigned short h0 = f2bf(v.x), h1 = f2bf(v.y), h2 = f2bf(v.z), h3 = f2bf(v.w);
        unsigned short l0 = f2bf(v.x - bf2f(h0)), l1 = f2bf(v.y - bf2f(h1));
        unsigned short l2 = f2bf(v.z - bf2f(h2)), l3 = f2bf(v.w - bf2f(h3));
        uint2 hp, lp;
        hp.x = (unsigned)h0 | ((unsigned)h1 << 16); hp.y = (unsigned)h2 | ((unsigned)h3 << 16);
        lp.x = (unsigned)l0 | ((unsigned)l1 << 16); lp.y = (unsigned)l2 | ((unsigned)l3 << 16);
        char* rowb = cbi + (size_t)k * 1024;
        *(uint2*)(rowb + lane * 8) = hp;
        *(uint2*)(rowb + 512 + lane * 8) = lp;

        if (rel < 4) hist[rel * 256 + tid] = 0u;
        if (rel == 4 && tid == 0) { *loss_sum = 0.0f; *flag_cnt = 0u; }
    }
}

// ---------------- main: bf16x2 split MFMA GEMM-argmin + margin flag ---------
// 512 thr (8 waves, 2x4 wave grid; wave tile 64x32). BM=BN=128, BK=64 per
// barrier (two 32-dim subtiles). Grid=512 -> 2 blocks/CU; 16 waves/CU
// (~4/SIMD) provide the m114 wave-level overlap that hides the per-step
// vmcnt drain (round-5 lesson: grid caps blocks/CU at 2, so scale waves
// per block instead of blocks).
// LDS rows are 128B = [hi k-slices 0..3 | lo k-slices 0..3] (16B each),
// XOR'd by (row&7) across the 8 slots; swizzle applied on the per-lane
// GLOBAL source address, LDS dest linear (rule #21). No asm, no
// sched_barrier -- compiler-scheduled (m141 lesson).
#define BM 128
#define BN 128

__global__ __launch_bounds__(512, 1) void vq_argmin(
    const float* __restrict__ z, const float* __restrict__ cb,
    const char* __restrict__ cbi,
    const float* __restrict__ z2, const float* __restrict__ e2,
    unsigned int* __restrict__ hist, float* __restrict__ loss_sum,
    unsigned int* __restrict__ flag_cnt, unsigned int* __restrict__ flag_list,
    float* __restrict__ out)
{
    // A0 @0, A1 @16K, B0 @32K, B1 @48K; reused as reduction arrays after loop
    __shared__ __align__(16) char sm[65536];
    __shared__ int kwin[BM];
    __shared__ unsigned char flgs[BM];
    __shared__ float wred[8];

    const int tid = threadIdx.x;
    const int lane = tid & 63;
    const int wid = tid >> 6;       // 0..7
    const int wm = wid >> 2;        // 0..1 (64-row band)
    const int wn = wid & 3;         // 0..3 (32-col band)
    const int col = lane & 15;      // frag column
    const int lg  = lane >> 4;      // k-slice group (16B unit)
    const int row0 = blockIdx.x * BM;

    const char* zsB = (const char*)out;        // zh/zl packed rows (1KB/row)

    // persistent per-thread state: 16 pixels x (best, 2nd-best, idx)
    float b1[16], b2[16]; int i1[16];
    float z2r[16];
    #pragma unroll
    for (int q = 0; q < 16; ++q) {
        b1[q] = FLT_MAX; b2[q] = FLT_MAX; i1[q] = 0;
        z2r[q] = z2[row0 + wm * 64 + (q >> 2) * 16 + lg * 4 + (q & 3)];
    }

    // ds_read byte offsets within a subtile (hi slot; lo slot = ^64)
    int aOff[4], bOff[2];
    #pragma unroll
    for (int f = 0; f < 4; ++f)
        aOff[f] = (wm * 64 + f * 16 + col) * 128 + ((lg ^ (col & 7)) << 4);
    #pragma unroll
    for (int f = 0; f < 2; ++f)
        bOff[f] = (wn * 32 + f * 16 + col) * 128 + ((lg ^ (col & 7)) << 4);

    // staging lane constants: phys slot pb at sub-row sr holds logical pb^sr
    const int sr = lane >> 3;                           // 0..7
    const int pb = lane & 7;
    const int lb = pb ^ sr;                             // logical 16B block
    const int srcColBase = ((lb & 4) << 7) + ((lb & 3) << 4); // hi/lo + slice

    #pragma unroll 1
    for (int nc = 0; nc < KTOT / BN; ++nc) {
        const int n0 = nc * BN;
        const size_t brow0 = ((size_t)(nc << 7)) << 10;
        f32x4 acc[4][2];
        #pragma unroll
        for (int fm = 0; fm < 4; ++fm)
            #pragma unroll
            for (int fn = 0; fn < 2; ++fn)
                acc[fm][fn] = (f32x4){0.0f, 0.0f, 0.0f, 0.0f};

        #pragma unroll 1
        for (int k8 = 0; k8 < 4; ++k8) {                // BK=64 steps
            __syncthreads();                            // prior reads done
            const int colb = k8 * 128 + srcColBase;
            #pragma unroll
            for (int ks = 0; ks < 2; ++ks) {            // 2x 32-dim subtiles
                const int srcCol = colb + ks * 64;
                #pragma unroll
                for (int i = 0; i < 2; ++i) {
                    const int slab = wid * 2 + i;       // 0..15, wave-uniform
                    const int r = slab * 8 + sr;
                    char* la = sm + ks * 16384 + slab * 1024;
                    gl16(zsB + (((size_t)(row0 + r)) << 10) + srcCol, la);
                    gl16(cbi + brow0 + (((size_t)r) << 10) + srcCol, la + 32768);
                }
            }
            __syncthreads();                            // drains vmcnt
            #pragma unroll
            for (int ks = 0; ks < 2; ++ks) {
                const char* at = sm + ks * 16384;
                s16x8 ah[4], al[4], bh[2], bl[2];
                #pragma unroll
                for (int f = 0; f < 4; ++f) {
                    ah[f] = *(const s16x8*)(at + aOff[f]);
                    al[f] = *(const s16x8*)(at + (aOff[f] ^ 64));
                }
                #pragma unroll
                for (int f = 0; f < 2; ++f) {
                    bh[f] = *(const s16x8*)(at + 32768 + bOff[f]);
                    bl[f] = *(const s16x8*)(at + 32768 + (bOff[f] ^ 64));
                }
                #pragma unroll
                for (int fm = 0; fm < 4; ++fm)
                    #pragma unroll
                    for (int fn = 0; fn < 2; ++fn) {   // fixed order: hh,hl,lh
                        acc[fm][fn] = __builtin_amdgcn_mfma_f32_16x16x32_bf16(
                            ah[fm], bh[fn], acc[fm][fn], 0, 0, 0);
                        acc[fm][fn] = __builtin_amdgcn_mfma_f32_16x16x32_bf16(
                            ah[fm], bl[fn], acc[fm][fn], 0, 0, 0);
                        acc[fm][fn] = __builtin_amdgcn_mfma_f32_16x16x32_bf16(
                            al[fm], bh[fn], acc[fm][fn], 0, 0, 0);
                    }
            }
        }
        // --- fold this nc chunk into running (best, 2nd); ref rounding -----
        const float* ep = e2 + n0 + wn * 32 + col;
        const float e2v[2] = {ep[0], ep[16]};
        #pragma unroll
        for (int fm = 0; fm < 4; ++fm)
            #pragma unroll
            for (int fn = 0; fn < 2; ++fn)
                #pragma unroll
                for (int r4 = 0; r4 < 4; ++r4) {
                    const int q = fm * 4 + r4;
                    const float dist = (z2r[q] + e2v[fn]) - 2.0f * acc[fm][fn][r4];
                    const int idx = n0 + wn * 32 + fn * 16 + col;
                    // k strictly increases within a thread -> strict < keeps
                    // earliest index on exact ties (matches np.argmin).
                    if (dist < b1[q]) { b2[q] = b1[q]; b1[q] = dist; i1[q] = idx; }
                    else if (dist < b2[q]) { b2[q] = dist; }
                }
    }

    // --- in-wave k-reduction: pixel q lives in 16 lanes (same lg, col 0..15)
    __syncthreads();                 // tiles dead -> reuse sm as reduction
    float* Rb1 = (float*)sm;         // [128][4]
    float* Rb2 = (float*)(sm + 2048);
    int*   Ri1 = (int*)(sm + 4096);
    #pragma unroll
    for (int q = 0; q < 16; ++q) {
        float x1 = b1[q], x2 = b2[q]; int xi = i1[q];
        #pragma unroll
        for (int m = 1; m < 16; m <<= 1) {
            const float y1 = __shfl_xor(x1, m, 64);
            const float y2 = __shfl_xor(x2, m, 64);
            const int   yi = __shfl_xor(xi, m, 64);
            const float nb2 = fminf(fmaxf(x1, y1), fminf(x2, y2));
            if (y1 < x1 || (y1 == x1 && yi < xi)) { x1 = y1; xi = yi; }
            x2 = nb2;
        }
        if (col == 0) {
            const int px = wm * 64 + (q >> 2) * 16 + lg * 4 + (q & 3);
            Rb1[px * 4 + wn] = x1; Rb2[px * 4 + wn] = x2; Ri1[px * 4 + wn] = xi;
        }
    }
    __syncthreads();
    if (tid < BM) {
        float x1 = Rb1[tid * 4], x2 = Rb2[tid * 4]; int xi = Ri1[tid * 4];
        #pragma unroll
        for (int s = 1; s < 4; ++s) {
            const float c1 = Rb1[tid * 4 + s], c2 = Rb2[tid * 4 + s];
            const int ci = Ri1[tid * 4 + s];
            const float nb2 = fminf(fmaxf(x1, c1), fminf(x2, c2));
            if (c1 < x1 || (c1 == x1 && ci < xi)) { x1 = c1; xi = ci; }
            x2 = nb2;
        }
        kwin[tid] = xi;
        const bool fl = (x2 - x1) <= MARGIN_;
        flgs[tid] = fl ? 1 : 0;
        if (fl) {
            const unsigned pos = atomicAdd(flag_cnt, 1u);
            flag_list[pos] = (unsigned)(row0 + tid);
        } else {
            out[OUT_IDX_OFF + row0 + tid] = (float)xi;
            atomicAdd(&hist[xi], 1u);
        }
    }
    __syncthreads();

    // --- epilogue for UNFLAGGED rows (exact fp32, ref rounding) ------------
    // overwrites this block's zh/zl scratch with the real z_q_st.
    float lacc = 0.0f;
    #pragma unroll 4
    for (int i = 0; i < 16; ++i) {
        const int flat4 = tid + i * 512;
        const int row = flat4 >> 6;            // wave-uniform
        if (!flgs[row]) {
            const int dj = (flat4 & 63) * 4;
            const size_t zoff = (size_t)(row0 + row) * DIM + dj;
            float4 zv = *(const float4*)(z + zoff);
            float4 ev = *(const float4*)(cb + (size_t)kwin[row] * DIM + dj);
            float dx = ev.x - zv.x, dy = ev.y - zv.y, dz = ev.z - zv.z, dw = ev.w - zv.w;
            float4 o;
            o.x = zv.x + dx; o.y = zv.y + dy; o.z = zv.z + dz; o.w = zv.w + dw;
            *(float4*)(out + zoff) = o;
            lacc += dx * dx + dy * dy + dz * dz + dw * dw;
        }
    }
    #pragma unroll
    for (int off = 32; off > 0; off >>= 1) lacc += __shfl_down(lacc, off, 64);
    if (lane == 0) wred[wid] = lacc;
    __syncthreads();
    if (tid == 0) {
        float s = 0.0f;
        #pragma unroll
        for (int w = 0; w < 8; ++w) s += wred[w];
        atomicAdd(loss_sum, s);
    }
}

// ---------------- repair: exact fp32 re-argmin + epilogue for flagged ------
// Bit-identical to the verified baseline's fp32 path: d-ascending fma chain,
// dist = (z2+e2[k]) - 2*dot, tie -> smaller index.
__global__ __launch_bounds__(256) void vq_fix(
    const float* __restrict__ z, const float* __restrict__ cb,
    const float* __restrict__ z2, const float* __restrict__ e2,
    const unsigned int* __restrict__ flag_cnt, const unsigned int* __restrict__ flag_list,
    unsigned int* __restrict__ hist, float* __restrict__ loss_sum,
    float* __restrict__ out)
{
    __shared__ float zrow[4][DIM];
    __shared__ float zz2[4];
    __shared__ int pxid[4];
    __shared__ float rb[4][256];
    __shared__ int   ri[4][256];
    __shared__ int   kw4[4];

    const int tid = threadIdx.x;
    const int total = (int)*flag_cnt;

    for (int base = blockIdx.x * 4; base < total; base += gridDim.x * 4) {
        const int npx = min(4, total - base);
        __syncthreads();                       // protect prev iter's shared
        if (tid < 4) {
            const int p = (int)flag_list[base + (tid < npx ? tid : 0)];
            pxid[tid] = p; zz2[tid] = z2[p];
        }
        __syncthreads();
        {
            const int q = tid >> 6, d = (tid & 63) * 4;
            float4 v = *(const float4*)(z + (size_t)pxid[q] * DIM + d);
            *(float4*)&zrow[q][d] = v;
        }
        __syncthreads();

        const int k0 = tid * 4;
        float acc[4][4];
        #pragma unroll
        for (int q = 0; q < 4; ++q)
            #pragma unroll
            for (int j = 0; j < 4; ++j) acc[q][j] = 0.0f;

        for (int d4 = 0; d4 < 64; ++d4) {
            float4 cv[4];
            #pragma unroll
            for (int j = 0; j < 4; ++j)
                cv[j] = *(const float4*)(cb + (size_t)(k0 + j) * DIM + d4 * 4);
            #pragma unroll
            for (int q = 0; q < 4; ++q) {
                float4 zv = *(const float4*)&zrow[q][d4 * 4];
                #pragma unroll
                for (int j = 0; j < 4; ++j) {
                    acc[q][j] = fmaf(zv.x, cv[j].x, acc[q][j]);
                    acc[q][j] = fmaf(zv.y, cv[j].y, acc[q][j]);
                    acc[q][j] = fmaf(zv.z, cv[j].z, acc[q][j]);
                    acc[q][j] = fmaf(zv.w, cv[j].w, acc[q][j]);
                }
            }
        }
        #pragma unroll
        for (int q = 0; q < 4; ++q) {
            float bd = FLT_MAX; int bi = 0;
            #pragma unroll
            for (int j = 0; j < 4; ++j) {       // k ascending -> strict <
                const int k = k0 + j;
                const float dist = (zz2[q] + e2[k]) - 2.0f * acc[q][j];
                if (dist < bd) { bd = dist; bi = k; }
            }
            rb[q][tid] = bd; ri[q][tid] = bi;
        }
        __syncthreads();
        {
            const int q = tid >> 6, lane = tid & 63;
            float bd = rb[q][lane]; int bi = ri[q][lane];
            #pragma unroll
            for (int s = 1; s < 4; ++s) {
                const float d2 = rb[q][lane + s * 64]; const int i2 = ri[q][lane + s * 64];
                if (d2 < bd || (d2 == bd && i2 < bi)) { bd = d2; bi = i2; }
            }
            #pragma unroll
            for (int off = 32; off > 0; off >>= 1) {
                const float d2 = __shfl_down(bd, off, 64);
                const int i2 = __shfl_down(bi, off, 64);
                if (d2 < bd || (d2 == bd && i2 < bi)) { bd = d2; bi = i2; }
            }
            if (lane == 0) kw4[q] = bi;
        }
        __syncthreads();
        {
            const int q = tid >> 6, lane = tid & 63;
            if (q < npx) {
                const int p = pxid[q];
                const int kw = kw4[q];
                const int d = lane * 4;
                float4 zv = *(const float4*)&zrow[q][d];
                float4 ev = *(const float4*)(cb + (size_t)kw * DIM + d);
                float dx = ev.x - zv.x, dy = ev.y - zv.y, dz = ev.z - zv.z, dw = ev.w - zv.w;
                float4 o;
                o.x = zv.x + dx; o.y = zv.y + dy; o.z = zv.z + dz; o.w = zv.w + dw;
                *(float4*)(out + (size_t)p * DIM + d) = o;
                float lacc = dx * dx + dy * dy + dz * dz + dw * dw;
                #pragma unroll
                for (int off = 32; off > 0; off >>= 1) lacc += __shfl_down(lacc, off, 64);
                if (lane == 0) {
                    atomicAdd(loss_sum, lacc);
                    out[OUT_IDX_OFF + p] = (float)kw;
                    atomicAdd(&hist[kw], 1u);
                }
            }
        }
    }
}

// ---------------- finalize: losses + perplexity -----------------------------
__global__ __launch_bounds__(1024) void vq_finalize(
    const unsigned int* __restrict__ hist, const float* __restrict__ loss_sum,
    float* __restrict__ out)
{
    __shared__ float sred[16];
    __shared__ float totalsh;
    const int tid = threadIdx.x;
    const float c = (float)hist[tid];

    float t = c;
    #pragma unroll
    for (int off = 32; off > 0; off >>= 1) t += __shfl_down(t, off, 64);
    if ((tid & 63) == 0) sred[tid >> 6] = t;
    __syncthreads();
    if (tid == 0) {
        float s = 0.0f;
        for (int i = 0; i < 16; ++i) s += sred[i];
        totalsh = s;
    }
    __syncthreads();
    const float total = totalsh;
    const float prob = c / (total + EPS_);
    float term = prob * logf(prob + EPS_);
    __syncthreads();
    #pragma unroll
    for (int off = 32; off > 0; off >>= 1) term += __shfl_down(term, off, 64);
    if ((tid & 63) == 0) sred[tid >> 6] = term;
    __syncthreads();
    if (tid == 0) {
        float s = 0.0f;
        for (int i = 0; i < 16; ++i) s += sred[i];
        const float perp = expf(-s);
        const float S = *loss_sum;
        const float mean = S / (float)(P_TOT * DIM);
        out[OUT_LOSS_OFF + 0] = mean;                  // commitment_loss
        out[OUT_LOSS_OFF + 1] = mean;                  // codebook_loss
        out[OUT_LOSS_OFF + 2] = mean + BETA_ * mean;   // cluster_loss
        out[OUT_LOSS_OFF + 3] = perp;                  // perplexity
    }
}

extern "C" void kernel_launch(void* const* d_in, const int* in_sizes, int n_in,
                              void* d_out, int out_size, void* d_ws, size_t ws_size,
                              hipStream_t stream) {
    const float* z  = (const float*)d_in[0];
    const float* cb = (const float*)d_in[1];
    float* out = (float*)d_out;

    // ws: z2[P] | e2[K] | hist[K] | loss_sum | flag_cnt | flag_list[P] |
    //     cbi[K rows x 1KB]   (~1.5 MiB)
    float* z2 = (float*)d_ws;
    float* e2 = z2 + P_TOT;
    unsigned int* hist = (unsigned int*)(e2 + KTOT);
    float* loss_sum = (float*)(hist + KTOT);
    unsigned int* flag_cnt = (unsigned int*)(loss_sum + 1);
    unsigned int* flag_list = flag_cnt + 1;
    char* cbi = (char*)(((uintptr_t)(flag_list + P_TOT) + 15) & ~(uintptr_t)15);

    vq_pre<<<P_TOT / 4 + KTOT / 4, 256, 0, stream>>>(z, cb, z2, e2, cbi, hist,
                                                     loss_sum, flag_cnt, out);
    vq_argmin<<<P_TOT / BM, 512, 0, stream>>>(z, cb, cbi, z2, e2,
                                              hist, loss_sum, flag_cnt, flag_list, out);
    vq_fix<<<1024, 256, 0, stream>>>(z, cb, z2, e2, flag_cnt, flag_list,
                                     hist, loss_sum, out);
    vq_finalize<<<1, 1024, 0, stream>>>(hist, loss_sum, out);
}

// Round 7
// 427.370 us; speedup vs baseline: 1.0606x; 1.0606x over previous
//
#include <hip/hip_runtime.h>
#include <cfloat>
#include <math.h>

// Problem constants (z: [16,64,64,256] fp32, codebook: [1024,256] fp32)
#define P_TOT 65536
#define DIM   256
#define KTOT  1024
#define BETA_ 0.25f
#define EPS_  1e-5f
// flag threshold: >= 2*(2*delta_ze) + 2*ULP(dist) with worst-case
// delta_ze <= ~8e-6 (3-term bf16 split + ref fp32 err) and ULP <= 3.05e-5.
#define MARGIN_ 1.5e-4f

// d_out layout (float32, concatenated in reference return order):
// [0, P*D) z_q_st | [P*D+0..3] losses+perplexity | [P*D+4, +P) indices
// vq_pre temporarily stores zh/zl bf16 (512B+512B per row) in the z_q_st
// region; each argmin block consumes only its own 128 rows before
// overwriting them with the real z_q_st (flagged rows finished by vq_fix).
#define OUT_LOSS_OFF ((size_t)P_TOT * DIM)
#define OUT_IDX_OFF  (OUT_LOSS_OFF + 4)

typedef __attribute__((ext_vector_type(8))) short s16x8;   // 8 bf16 (4 VGPRs)
typedef __attribute__((ext_vector_type(4))) float f32x4;   // MFMA acc

__device__ __forceinline__ unsigned short f2bf(float x) {  // RNE f32->bf16
    unsigned u = __float_as_uint(x);
    u += 0x7FFFu + ((u >> 16) & 1u);
    return (unsigned short)(u >> 16);
}
__device__ __forceinline__ float bf2f(unsigned short h) {
    return __uint_as_float(((unsigned)h) << 16);
}
// async global->LDS direct copy, 16B per lane; lds ptr MUST be wave-uniform.
__device__ __forceinline__ void gl16(const void* g, void* l) {
    __builtin_amdgcn_global_load_lds(
        (const __attribute__((address_space(1))) unsigned int*)g,
        (__attribute__((address_space(3))) unsigned int*)l, 16, 0, 0);
}

// ------- fused pre-pass: zsplit (blocks < P/4) + codebook prep (rest) -------
// z part:  z2[p] = sum(z[p]^2); out row p: [512B zh | 512B zl]
// cb part: e2[k]; cbi row k: [512B cbh | 512B cbl]; zero hist/loss/flags
__global__ __launch_bounds__(256) void vq_pre(
    const float* __restrict__ z, const float* __restrict__ cb,
    float* __restrict__ z2, float* __restrict__ e2,
    char* __restrict__ cbi, unsigned int* __restrict__ hist,
    float* __restrict__ loss_sum, unsigned int* __restrict__ flag_cnt,
    float* __restrict__ out)
{
    const int tid = threadIdx.x;
    const int lane = tid & 63;
    const int wave = tid >> 6;
    const int bid = blockIdx.x;

    if (bid < P_TOT / 4) {
        const int p = bid * 4 + wave;
        float4 v = *(const float4*)(z + (size_t)p * DIM + lane * 4);
        float s = v.x * v.x + v.y * v.y + v.z * v.z + v.w * v.w;
        #pragma unroll
        for (int off = 32; off > 0; off >>= 1) s += __shfl_down(s, off, 64);
        if (lane == 0) z2[p] = s;

        unsigned short h0 = f2bf(v.x), h1 = f2bf(v.y), h2 = f2bf(v.z), h3 = f2bf(v.w);
        unsigned short l0 = f2bf(v.x - bf2f(h0)), l1 = f2bf(v.y - bf2f(h1));
        unsigned short l2 = f2bf(v.z - bf2f(h2)), l3 = f2bf(v.w - bf2f(h3));
        uint2 hp, lp;
        hp.x = (unsigned)h0 | ((unsigned)h1 << 16); hp.y = (unsigned)h2 | ((unsigned)h3 << 16);
        lp.x = (unsigned)l0 | ((unsigned)l1 << 16); lp.y = (unsigned)l2 | ((unsigned)l3 << 16);
        char* rowb = (char*)out + (size_t)p * 1024;
        *(uint2*)(rowb + lane * 8) = hp;
        *(uint2*)(rowb + 512 + lane * 8) = lp;
    } else {
        const int rel = bid - P_TOT / 4;
        const int k = rel * 4 + wave;
        float4 v = *(const float4*)(cb + (size_t)k * DIM + lane * 4);
        float s = v.x * v.x + v.y * v.y + v.z * v.z + v.w * v.w;
        #pragma unroll
        for (int off = 32; off > 0; off >>= 1) s += __shfl_down(s, off, 64);
        if (lane == 0) e2[k] = s;

        unsigned short h0 = f2bf(v.x), h1 = f2bf(v.y), h2 = f2bf(v.z), h3 = f2bf(v.w);
        unsigned short l0 = f2bf(v.x - bf2f(h0)), l1 = f2bf(v.y - bf2f(h1));
        unsigned short l2 = f2bf(v.z - bf2f(h2)), l3 = f2bf(v.w - bf2f(h3));
        uint2 hp, lp;
        hp.x = (unsigned)h0 | ((unsigned)h1 << 16); hp.y = (unsigned)h2 | ((unsigned)h3 << 16);
        lp.x = (unsigned)l0 | ((unsigned)l1 << 16); lp.y = (unsigned)l2 | ((unsigned)l3 << 16);
        char* rowb = cbi + (size_t)k * 1024;
        *(uint2*)(rowb + lane * 8) = hp;
        *(uint2*)(rowb + 512 + lane * 8) = lp;

        if (rel < 4) hist[rel * 256 + tid] = 0u;
        if (rel == 4 && tid == 0) { *loss_sum = 0.0f; *flag_cnt = 0u; }
    }
}

// ---------------- main: bf16x2 split MFMA GEMM-argmin + margin flag ---------
// 256 thr (4 waves, 2x2 wave grid; wave tile 64x64). BM=BN=128, BK=32,
// DOUBLE-buffered LDS (2 x 32KB). T3 minimum 2-phase schedule (m248):
// issue step t+1's global_load_lds into buf^1 BEFORE computing buf, then
// ONE __syncthreads per step -- its implicit vmcnt(0) drain lands after the
// 48 MFMAs, so load latency hides under compute. NO sched_barrier / asm
// (round-3 lesson: pinning blew VALU to 52%). Addresses strength-reduced
// to per-thread bases + one add.
// LDS rows are 128B = [hi k-slices 0..3 | lo k-slices 0..3] (16B each),
// XOR'd by (row&7) across the 8 slots; swizzle applied on the per-lane
// GLOBAL source address, LDS dest linear (rule #21).
#define BM 128
#define BN 128

__global__ __launch_bounds__(256, 2) void vq_argmin(
    const float* __restrict__ z, const float* __restrict__ cb,
    const char* __restrict__ cbi,
    const float* __restrict__ z2, const float* __restrict__ e2,
    unsigned int* __restrict__ hist, float* __restrict__ loss_sum,
    unsigned int* __restrict__ flag_cnt, unsigned int* __restrict__ flag_list,
    float* __restrict__ out)
{
    // buffer b at sm + (b<<15): A tile @+0 (16KB), B tile @+16K (16KB)
    __shared__ __align__(16) char sm[65536];
    __shared__ float sb1[BM][2];
    __shared__ float sb2[BM][2];
    __shared__ int   si1[BM][2];
    __shared__ int kwin[BM];
    __shared__ unsigned char flgs[BM];
    __shared__ float wred[4];

    const int tid = threadIdx.x;
    const int lane = tid & 63;
    const int wid = tid >> 6;
    const int wm = wid >> 1, wn = wid & 1;
    const int col = lane & 15;      // frag column
    const int lg  = lane >> 4;      // k-slice group (16B unit)
    const int row0 = blockIdx.x * BM;

    const char* zsB = (const char*)out;        // zh/zl packed rows (1KB/row)

    // persistent per-thread state: 16 pixels x (best, 2nd-best, idx)
    float b1[16], b2[16]; int i1[16];
    float z2r[16];
    #pragma unroll
    for (int q = 0; q < 16; ++q) {
        b1[q] = FLT_MAX; b2[q] = FLT_MAX; i1[q] = 0;
        z2r[q] = z2[row0 + wm * 64 + (q >> 2) * 16 + lg * 4 + (q & 3)];
    }

    // ds_read byte offsets within a buffer (hi slot; lo slot = ^64)
    int aOff[4], bOff[4];
    #pragma unroll
    for (int f = 0; f < 4; ++f) {
        const int pbl = (lg ^ (col & 7)) << 4;          // swizzled 16B slot
        aOff[f] = (wm * 64 + f * 16 + col) * 128 + pbl;
        bOff[f] = (wn * 64 + f * 16 + col) * 128 + pbl;
    }

    // staging lane constants: phys slot pb at sub-row sr holds logical pb^sr
    const int sr = lane >> 3;                           // 0..7
    const int lb = (lane & 7) ^ sr;                     // logical 16B block
    const int srcColBase = ((lb & 4) << 7) + ((lb & 3) << 4); // hi/lo + slice

    // precomputed staging bases (4 row-slabs of 32 rows each)
    size_t aRowB[4], bRowB[4];
    int ldsD[4];
    #pragma unroll
    for (int i = 0; i < 4; ++i) {
        const int rb = i * 32 + wid * 8;                // wave-uniform slab
        ldsD[i]  = rb * 128;
        aRowB[i] = ((size_t)(row0 + rb + sr)) << 10;
        bRowB[i] = ((size_t)(rb + sr)) << 10;
    }

    // ---- prologue: stage step 0 into buffer 0 -----------------------------
    #pragma unroll
    for (int i = 0; i < 4; ++i) {
        gl16(zsB + aRowB[i] + srcColBase, sm + ldsD[i]);
        gl16(cbi + bRowB[i] + srcColBase, sm + 16384 + ldsD[i]);
    }
    __syncthreads();   // vmcnt(0) drain -> buffer 0 ready

    f32x4 acc[4][4];

    // ---- main 2-phase loop: 64 steps = 8 nc x 8 k-steps (BK=32) ----------
    #pragma unroll 1
    for (int t = 0; t < 64; ++t) {
        const int buf = t & 1;
        if ((t & 7) == 0) {
            #pragma unroll
            for (int fm = 0; fm < 4; ++fm)
                #pragma unroll
                for (int fn = 0; fn < 4; ++fn)
                    acc[fm][fn] = (f32x4){0.0f, 0.0f, 0.0f, 0.0f};
        }
        // stage NEXT step into the other buffer (overlaps compute below)
        if (t < 63) {
            const int tn = t + 1;
            const int srcCol = ((tn & 7) << 6) + srcColBase;
            const size_t bnc = ((size_t)(tn >> 3)) << 17;   // nc * 128 rows * 1KB
            char* dst = sm + ((tn & 1) << 15);
            #pragma unroll
            for (int i = 0; i < 4; ++i) {
                gl16(zsB + aRowB[i] + srcCol, dst + ldsD[i]);
                gl16(cbi + bnc + bRowB[i] + srcCol, dst + 16384 + ldsD[i]);
            }
        }
        // compute current buffer
        const char* at = sm + (buf << 15);
        s16x8 ah[4], al[4], bh[4], bl[4];
        #pragma unroll
        for (int f = 0; f < 4; ++f) {
            ah[f] = *(const s16x8*)(at + aOff[f]);
            al[f] = *(const s16x8*)(at + (aOff[f] ^ 64));
            bh[f] = *(const s16x8*)(at + 16384 + bOff[f]);
            bl[f] = *(const s16x8*)(at + 16384 + (bOff[f] ^ 64));
        }
        #pragma unroll
        for (int fm = 0; fm < 4; ++fm)
            #pragma unroll
            for (int fn = 0; fn < 4; ++fn) {   // fixed order: hh, hl, lh
                acc[fm][fn] = __builtin_amdgcn_mfma_f32_16x16x32_bf16(
                    ah[fm], bh[fn], acc[fm][fn], 0, 0, 0);
                acc[fm][fn] = __builtin_amdgcn_mfma_f32_16x16x32_bf16(
                    ah[fm], bl[fn], acc[fm][fn], 0, 0, 0);
                acc[fm][fn] = __builtin_amdgcn_mfma_f32_16x16x32_bf16(
                    al[fm], bh[fn], acc[fm][fn], 0, 0, 0);
            }

        if ((t & 7) == 7) {   // fold this nc chunk into running (best, 2nd)
            const int n0 = (t >> 3) << 7;
            const float* ep = e2 + n0 + wn * 64 + col;
            const float e2v[4] = {ep[0], ep[16], ep[32], ep[48]};
            #pragma unroll
            for (int fm = 0; fm < 4; ++fm)
                #pragma unroll
                for (int fn = 0; fn < 4; ++fn)
                    #pragma unroll
                    for (int r4 = 0; r4 < 4; ++r4) {
                        const int q = fm * 4 + r4;
                        const float dist = (z2r[q] + e2v[fn]) - 2.0f * acc[fm][fn][r4];
                        const int idx = n0 + wn * 64 + fn * 16 + col;
                        // k strictly increases within a thread -> strict <
                        // keeps earliest index on ties (matches np.argmin).
                        if (dist < b1[q]) { b2[q] = b1[q]; b1[q] = dist; i1[q] = idx; }
                        else if (dist < b2[q]) { b2[q] = dist; }
                    }
        }
        __syncthreads();   // drains vmcnt -> staged buffer ready for t+1
    }

    // --- in-wave k-reduction: pixel q lives in 16 lanes (same lg, col 0..15)
    #pragma unroll
    for (int q = 0; q < 16; ++q) {
        float x1 = b1[q], x2 = b2[q]; int xi = i1[q];
        #pragma unroll
        for (int m = 1; m < 16; m <<= 1) {
            const float y1 = __shfl_xor(x1, m, 64);
            const float y2 = __shfl_xor(x2, m, 64);
            const int   yi = __shfl_xor(xi, m, 64);
            const float nb2 = fminf(fmaxf(x1, y1), fminf(x2, y2));
            if (y1 < x1 || (y1 == x1 && yi < xi)) { x1 = y1; xi = yi; }
            x2 = nb2;
        }
        if (col == 0) {
            const int px = wm * 64 + (q >> 2) * 16 + lg * 4 + (q & 3);
            sb1[px][wn] = x1; sb2[px][wn] = x2; si1[px][wn] = xi;
        }
    }
    __syncthreads();
    if (tid < BM) {
        float x1 = sb1[tid][0], x2 = sb2[tid][0]; int xi = si1[tid][0];
        const float y1 = sb1[tid][1], y2 = sb2[tid][1]; const int yi = si1[tid][1];
        const float nb2 = fminf(fmaxf(x1, y1), fminf(x2, y2));
        if (y1 < x1 || (y1 == x1 && yi < xi)) { x1 = y1; xi = yi; }
        x2 = nb2;
        kwin[tid] = xi;
        const bool fl = (x2 - x1) <= MARGIN_;
        flgs[tid] = fl ? 1 : 0;
        if (fl) {
            const unsigned pos = atomicAdd(flag_cnt, 1u);
            flag_list[pos] = (unsigned)(row0 + tid);
        } else {
            out[OUT_IDX_OFF + row0 + tid] = (float)xi;
            atomicAdd(&hist[xi], 1u);
        }
    }
    __syncthreads();

    // --- epilogue for UNFLAGGED rows (exact fp32, ref rounding) ------------
    // overwrites this block's zh/zl scratch with the real z_q_st.
    float lacc = 0.0f;
    #pragma unroll 4
    for (int i = 0; i < 32; ++i) {
        const int flat4 = tid + i * 256;
        const int row = flat4 >> 6;            // wave-uniform
        if (!flgs[row]) {
            const int dj = (flat4 & 63) * 4;
            const size_t zoff = (size_t)(row0 + row) * DIM + dj;
            float4 zv = *(const float4*)(z + zoff);
            float4 ev = *(const float4*)(cb + (size_t)kwin[row] * DIM + dj);
            float dx = ev.x - zv.x, dy = ev.y - zv.y, dz = ev.z - zv.z, dw = ev.w - zv.w;
            float4 o;
            o.x = zv.x + dx; o.y = zv.y + dy; o.z = zv.z + dz; o.w = zv.w + dw;
            *(float4*)(out + zoff) = o;
            lacc += dx * dx + dy * dy + dz * dz + dw * dw;
        }
    }
    #pragma unroll
    for (int off = 32; off > 0; off >>= 1) lacc += __shfl_down(lacc, off, 64);
    if (lane == 0) wred[wid] = lacc;
    __syncthreads();
    if (tid == 0) atomicAdd(loss_sum, wred[0] + wred[1] + wred[2] + wred[3]);
}

// ---------------- repair: exact fp32 re-argmin + epilogue for flagged ------
// Bit-identical to the verified baseline's fp32 path: d-ascending fma chain,
// dist = (z2+e2[k]) - 2*dot, tie -> smaller index.
__global__ __launch_bounds__(256) void vq_fix(
    const float* __restrict__ z, const float* __restrict__ cb,
    const float* __restrict__ z2, const float* __restrict__ e2,
    const unsigned int* __restrict__ flag_cnt, const unsigned int* __restrict__ flag_list,
    unsigned int* __restrict__ hist, float* __restrict__ loss_sum,
    float* __restrict__ out)
{
    __shared__ float zrow[4][DIM];
    __shared__ float zz2[4];
    __shared__ int pxid[4];
    __shared__ float rb[4][256];
    __shared__ int   ri[4][256];
    __shared__ int   kw4[4];

    const int tid = threadIdx.x;
    const int total = (int)*flag_cnt;

    for (int base = blockIdx.x * 4; base < total; base += gridDim.x * 4) {
        const int npx = min(4, total - base);
        __syncthreads();                       // protect prev iter's shared
        if (tid < 4) {
            const int p = (int)flag_list[base + (tid < npx ? tid : 0)];
            pxid[tid] = p; zz2[tid] = z2[p];
        }
        __syncthreads();
        {
            const int q = tid >> 6, d = (tid & 63) * 4;
            float4 v = *(const float4*)(z + (size_t)pxid[q] * DIM + d);
            *(float4*)&zrow[q][d] = v;
        }
        __syncthreads();

        const int k0 = tid * 4;
        float acc[4][4];
        #pragma unroll
        for (int q = 0; q < 4; ++q)
            #pragma unroll
            for (int j = 0; j < 4; ++j) acc[q][j] = 0.0f;

        for (int d4 = 0; d4 < 64; ++d4) {
            float4 cv[4];
            #pragma unroll
            for (int j = 0; j < 4; ++j)
                cv[j] = *(const float4*)(cb + (size_t)(k0 + j) * DIM + d4 * 4);
            #pragma unroll
            for (int q = 0; q < 4; ++q) {
                float4 zv = *(const float4*)&zrow[q][d4 * 4];
                #pragma unroll
                for (int j = 0; j < 4; ++j) {
                    acc[q][j] = fmaf(zv.x, cv[j].x, acc[q][j]);
                    acc[q][j] = fmaf(zv.y, cv[j].y, acc[q][j]);
                    acc[q][j] = fmaf(zv.z, cv[j].z, acc[q][j]);
                    acc[q][j] = fmaf(zv.w, cv[j].w, acc[q][j]);
                }
            }
        }
        #pragma unroll
        for (int q = 0; q < 4; ++q) {
            float bd = FLT_MAX; int bi = 0;
            #pragma unroll
            for (int j = 0; j < 4; ++j) {       // k ascending -> strict <
                const int k = k0 + j;
                const float dist = (zz2[q] + e2[k]) - 2.0f * acc[q][j];
                if (dist < bd) { bd = dist; bi = k; }
            }
            rb[q][tid] = bd; ri[q][tid] = bi;
        }
        __syncthreads();
        {
            const int q = tid >> 6, lane = tid & 63;
            float bd = rb[q][lane]; int bi = ri[q][lane];
            #pragma unroll
            for (int s = 1; s < 4; ++s) {
                const float d2 = rb[q][lane + s * 64]; const int i2 = ri[q][lane + s * 64];
                if (d2 < bd || (d2 == bd && i2 < bi)) { bd = d2; bi = i2; }
            }
            #pragma unroll
            for (int off = 32; off > 0; off >>= 1) {
                const float d2 = __shfl_down(bd, off, 64);
                const int i2 = __shfl_down(bi, off, 64);
                if (d2 < bd || (d2 == bd && i2 < bi)) { bd = d2; bi = i2; }
            }
            if (lane == 0) kw4[q] = bi;
        }
        __syncthreads();
        {
            const int q = tid >> 6, lane = tid & 63;
            if (q < npx) {
                const int p = pxid[q];
                const int kw = kw4[q];
                const int d = lane * 4;
                float4 zv = *(const float4*)&zrow[q][d];
                float4 ev = *(const float4*)(cb + (size_t)kw * DIM + d);
                float dx = ev.x - zv.x, dy = ev.y - zv.y, dz = ev.z - zv.z, dw = ev.w - zv.w;
                float4 o;
                o.x = zv.x + dx; o.y = zv.y + dy; o.z = zv.z + dz; o.w = zv.w + dw;
                *(float4*)(out + (size_t)p * DIM + d) = o;
                float lacc = dx * dx + dy * dy + dz * dz + dw * dw;
                #pragma unroll
                for (int off = 32; off > 0; off >>= 1) lacc += __shfl_down(lacc, off, 64);
                if (lane == 0) {
                    atomicAdd(loss_sum, lacc);
                    out[OUT_IDX_OFF + p] = (float)kw;
                    atomicAdd(&hist[kw], 1u);
                }
            }
        }
    }
}

// ---------------- finalize: losses + perplexity -----------------------------
__global__ __launch_bounds__(1024) void vq_finalize(
    const unsigned int* __restrict__ hist, const float* __restrict__ loss_sum,
    float* __restrict__ out)
{
    __shared__ float sred[16];
    __shared__ float totalsh;
    const int tid = threadIdx.x;
    const float c = (float)hist[tid];

    float t = c;
    #pragma unroll
    for (int off = 32; off > 0; off >>= 1) t += __shfl_down(t, off, 64);
    if ((tid & 63) == 0) sred[tid >> 6] = t;
    __syncthreads();
    if (tid == 0) {
        float s = 0.0f;
        for (int i = 0; i < 16; ++i) s += sred[i];
        totalsh = s;
    }
    __syncthreads();
    const float total = totalsh;
    const float prob = c / (total + EPS_);
    float term = prob * logf(prob + EPS_);
    __syncthreads();
    #pragma unroll
    for (int off = 32; off > 0; off >>= 1) term += __shfl_down(term, off, 64);
    if ((tid & 63) == 0) sred[tid >> 6] = term;
    __syncthreads();
    if (tid == 0) {
        float s = 0.0f;
        for (int i = 0; i < 16; ++i) s += sred[i];
        const float perp = expf(-s);
        const float S = *loss_sum;
        const float mean = S / (float)(P_TOT * DIM);
        out[OUT_LOSS_OFF + 0] = mean;                  // commitment_loss
        out[OUT_LOSS_OFF + 1] = mean;                  // codebook_loss
        out[OUT_LOSS_OFF + 2] = mean + BETA_ * mean;   // cluster_loss
        out[OUT_LOSS_OFF + 3] = perp;                  // perplexity
    }
}

extern "C" void kernel_launch(void* const* d_in, const int* in_sizes, int n_in,
                              void* d_out, int out_size, void* d_ws, size_t ws_size,
                              hipStream_t stream) {
    const float* z  = (const float*)d_in[0];
    const float* cb = (const float*)d_in[1];
    float* out = (float*)d_out;

    // ws: z2[P] | e2[K] | hist[K] | loss_sum | flag_cnt | flag_list[P] |
    //     cbi[K rows x 1KB]   (~1.5 MiB)
    float* z2 = (float*)d_ws;
    float* e2 = z2 + P_TOT;
    unsigned int* hist = (unsigned int*)(e2 + KTOT);
    float* loss_sum = (float*)(hist + KTOT);
    unsigned int* flag_cnt = (unsigned int*)(loss_sum + 1);
    unsigned int* flag_list = flag_cnt + 1;
    char* cbi = (char*)(((uintptr_t)(flag_list + P_TOT) + 15) & ~(uintptr_t)15);

    vq_pre<<<P_TOT / 4 + KTOT / 4, 256, 0, stream>>>(z, cb, z2, e2, cbi, hist,
                                                     loss_sum, flag_cnt, out);
    vq_argmin<<<P_TOT / BM, 256, 0, stream>>>(z, cb, cbi, z2, e2,
                                              hist, loss_sum, flag_cnt, flag_list, out);
    vq_fix<<<1024, 256, 0, stream>>>(z, cb, z2, e2, flag_cnt, flag_list,
                                     hist, loss_sum, out);
    vq_finalize<<<1, 1024, 0, stream>>>(hist, loss_sum, out);
}

// Round 8
// 387.598 us; speedup vs baseline: 1.1694x; 1.1026x over previous
//
#include <hip/hip_runtime.h>
#include <cfloat>
#include <math.h>

// Problem constants (z: [16,64,64,256] fp32, codebook: [1024,256] fp32)
#define P_TOT 65536
#define DIM   256
#define KTOT  1024
#define BETA_ 0.25f
#define EPS_  1e-5f
// flag threshold: >= 2*(2*delta_ze) + 2*ULP(dist) with worst-case
// delta_ze <= ~8e-6 (3-term bf16 split + ref fp32 err) and ULP <= 3.05e-5.
#define MARGIN_ 1.5e-4f

// d_out layout (float32, concatenated in reference return order):
// [0, P*D) z_q_st | [P*D+0..3] losses+perplexity | [P*D+4, +P) indices
// vq_pre temporarily stores zh/zl bf16 (512B+512B per row) in the z_q_st
// region; each argmin block consumes only its own 128 rows before
// overwriting them with the real z_q_st (flagged rows finished by vq_fix).
#define OUT_LOSS_OFF ((size_t)P_TOT * DIM)
#define OUT_IDX_OFF  (OUT_LOSS_OFF + 4)

typedef __attribute__((ext_vector_type(8))) short s16x8;   // 8 bf16 (4 VGPRs)
typedef __attribute__((ext_vector_type(4))) float f32x4;   // MFMA acc

__device__ __forceinline__ unsigned short f2bf(float x) {  // RNE f32->bf16
    unsigned u = __float_as_uint(x);
    u += 0x7FFFu + ((u >> 16) & 1u);
    return (unsigned short)(u >> 16);
}
__device__ __forceinline__ float bf2f(unsigned short h) {
    return __uint_as_float(((unsigned)h) << 16);
}
// async global->LDS direct copy, 16B per lane; lds ptr MUST be wave-uniform.
__device__ __forceinline__ void gl16(const void* g, void* l) {
    __builtin_amdgcn_global_load_lds(
        (const __attribute__((address_space(1))) unsigned int*)g,
        (__attribute__((address_space(3))) unsigned int*)l, 16, 0, 0);
}

// ------- fused pre-pass: zsplit (blocks < P/4) + codebook prep (rest) -------
// z part:  z2[p] = sum(z[p]^2); out row p: [512B zh | 512B zl]
// cb part: e2[k]; cbh row k (512B), cbl row k (512B); zero hist/loss/flags
__global__ __launch_bounds__(256) void vq_pre(
    const float* __restrict__ z, const float* __restrict__ cb,
    float* __restrict__ z2, float* __restrict__ e2,
    unsigned short* __restrict__ cbh, unsigned short* __restrict__ cbl,
    unsigned int* __restrict__ hist,
    float* __restrict__ loss_sum, unsigned int* __restrict__ flag_cnt,
    float* __restrict__ out)
{
    const int tid = threadIdx.x;
    const int lane = tid & 63;
    const int wave = tid >> 6;
    const int bid = blockIdx.x;

    if (bid < P_TOT / 4) {
        const int p = bid * 4 + wave;
        float4 v = *(const float4*)(z + (size_t)p * DIM + lane * 4);
        float s = v.x * v.x + v.y * v.y + v.z * v.z + v.w * v.w;
        #pragma unroll
        for (int off = 32; off > 0; off >>= 1) s += __shfl_down(s, off, 64);
        if (lane == 0) z2[p] = s;

        unsigned short h0 = f2bf(v.x), h1 = f2bf(v.y), h2 = f2bf(v.z), h3 = f2bf(v.w);
        unsigned short l0 = f2bf(v.x - bf2f(h0)), l1 = f2bf(v.y - bf2f(h1));
        unsigned short l2 = f2bf(v.z - bf2f(h2)), l3 = f2bf(v.w - bf2f(h3));
        uint2 hp, lp;
        hp.x = (unsigned)h0 | ((unsigned)h1 << 16); hp.y = (unsigned)h2 | ((unsigned)h3 << 16);
        lp.x = (unsigned)l0 | ((unsigned)l1 << 16); lp.y = (unsigned)l2 | ((unsigned)l3 << 16);
        char* rowb = (char*)out + (size_t)p * 1024;
        *(uint2*)(rowb + lane * 8) = hp;
        *(uint2*)(rowb + 512 + lane * 8) = lp;
    } else {
        const int rel = bid - P_TOT / 4;
        const int k = rel * 4 + wave;
        float4 v = *(const float4*)(cb + (size_t)k * DIM + lane * 4);
        float s = v.x * v.x + v.y * v.y + v.z * v.z + v.w * v.w;
        #pragma unroll
        for (int off = 32; off > 0; off >>= 1) s += __shfl_down(s, off, 64);
        if (lane == 0) e2[k] = s;

        unsigned short h0 = f2bf(v.x), h1 = f2bf(v.y), h2 = f2bf(v.z), h3 = f2bf(v.w);
        unsigned short l0 = f2bf(v.x - bf2f(h0)), l1 = f2bf(v.y - bf2f(h1));
        unsigned short l2 = f2bf(v.z - bf2f(h2)), l3 = f2bf(v.w - bf2f(h3));
        uint2 hp, lp;
        hp.x = (unsigned)h0 | ((unsigned)h1 << 16); hp.y = (unsigned)h2 | ((unsigned)h3 << 16);
        lp.x = (unsigned)l0 | ((unsigned)l1 << 16); lp.y = (unsigned)l2 | ((unsigned)l3 << 16);
        *(uint2*)(cbh + (size_t)k * DIM + lane * 4) = hp;
        *(uint2*)(cbl + (size_t)k * DIM + lane * 4) = lp;

        if (rel < 4) hist[rel * 256 + tid] = 0u;
        if (rel == 4 && tid == 0) { *loss_sum = 0.0f; *flag_cnt = 0u; }
    }
}

// ---------------- main: bf16x2 split MFMA GEMM-argmin + margin flag ---------
// VERBATIM round-2 kernel (measured argmin 166us, MfmaUtil 25.8, total-best
// config): 256 thr, 2x2 waves, BM=BN=128, BK=64, single-buffered LDS,
// 2 barriers/step. Rounds 3-7 perturbations (2-phase dbuf, BK=32, 8-wave,
// launch_bounds 4) ALL regressed -- this serial structure + 2 blocks/CU
// implicit wave overlap is the empirical optimum for this shape.
// Staging is pure global_load_lds: XOR-16B swizzle applied on the per-lane
// GLOBAL source address, LDS dest linear (rule #21).
#define BM 128
#define BN 128

__global__ __launch_bounds__(256, 2) void vq_argmin(
    const float* __restrict__ z, const float* __restrict__ cb,
    const unsigned short* __restrict__ cbh, const unsigned short* __restrict__ cbl,
    const float* __restrict__ z2, const float* __restrict__ e2,
    unsigned int* __restrict__ hist, float* __restrict__ loss_sum,
    unsigned int* __restrict__ flag_cnt, unsigned int* __restrict__ flag_list,
    float* __restrict__ out)
{
    // LDS: 4 bf16 tiles [128 rows][128B] (Ah,Al,Bh,Bl) = 64KB, reused as red.
    __shared__ __align__(16) char sm[65536];
    __shared__ int kwin[BM];
    __shared__ unsigned char flgs[BM];
    __shared__ float wred[4];

    const int tid = threadIdx.x;
    const int lane = tid & 63;
    const int wid = tid >> 6;
    const int wm = wid >> 1, wn = wid & 1;
    const int col = lane & 15;      // frag column
    const int lg  = lane >> 4;      // k-group
    const int swz = lane & 7;
    const int row0 = blockIdx.x * BM;

    const char* zsB  = (const char*)out;       // zh/zl packed rows (1KB/row)
    const char* cbhB = (const char*)cbh;       // 512B/row
    const char* cblB = (const char*)cbl;

    // persistent per-thread state: 16 pixels x (best, 2nd-best, idx)
    float b1[16], b2[16]; int i1[16];
    float z2r[16];
    #pragma unroll
    for (int q = 0; q < 16; ++q) {
        b1[q] = FLT_MAX; b2[q] = FLT_MAX; i1[q] = 0;
        z2r[q] = z2[row0 + wm * 64 + (q >> 2) * 16 + lg * 4 + (q & 3)];
    }

    int aRow[4], bRow[4];
    #pragma unroll
    for (int f = 0; f < 4; ++f) {
        aRow[f] = (wm * 64 + f * 16 + col) * 128;   // byte base of LDS row
        bRow[f] = (wn * 64 + f * 16 + col) * 128;
    }
    const int bc0 = ((0 + lg) ^ swz) << 4;          // swizzled 16B col, ks=0
    const int bc1 = ((4 + lg) ^ swz) << 4;          // ks=1

    const int sr  = lane >> 3;                      // staging sub-row 0..7
    const int scb = lane & 7;                       // staging phys 16B block

    #pragma unroll 1
    for (int nc = 0; nc < KTOT / BN; ++nc) {
        const int n0 = nc * BN;
        f32x4 acc[4][4];
        #pragma unroll
        for (int fm = 0; fm < 4; ++fm)
            #pragma unroll
            for (int fn = 0; fn < 4; ++fn)
                acc[fm][fn] = (f32x4){0.0f, 0.0f, 0.0f, 0.0f};

        #pragma unroll 1
        for (int kc = 0; kc < 4; ++kc) {            // BK=64
            __syncthreads();
            // --- stage: 16 x global_load_lds (4 tiles x 4 row-slabs) -------
            #pragma unroll
            for (int i = 0; i < 4; ++i) {
                const int rloc = wid * 32 + i * 8 + sr;           // 0..127
                const int cb16 = ((scb ^ (rloc & 7)) << 4);       // src block
                const size_t aoff = ((size_t)(row0 + rloc) << 10) + (kc << 7);
                const size_t boff = ((size_t)(n0 + rloc) << 9) + (kc << 7);
                char* lb = sm + (wid * 32 + i * 8) * 128;         // uniform
                gl16(zsB + aoff + cb16,        lb);               // Ah @ 0
                gl16(zsB + aoff + 512 + cb16,  lb + 16384);       // Al @ 16K
                gl16(cbhB + boff + cb16,       lb + 32768);       // Bh @ 32K
                gl16(cblB + boff + cb16,       lb + 49152);       // Bl @ 48K
            }
            __syncthreads();   // drains vmcnt -> tiles visible
            // --- MFMA: 3-term bf16x2 split into shared f32 accumulator ----
            #pragma unroll
            for (int ks = 0; ks < 2; ++ks) {
                const int bc = ks ? bc1 : bc0;
                s16x8 ah[4], al[4], bh[4], bl[4];
                #pragma unroll
                for (int f = 0; f < 4; ++f) {
                    ah[f] = *(const s16x8*)(sm + aRow[f] + bc);
                    al[f] = *(const s16x8*)(sm + 16384 + aRow[f] + bc);
                    bh[f] = *(const s16x8*)(sm + 32768 + bRow[f] + bc);
                    bl[f] = *(const s16x8*)(sm + 49152 + bRow[f] + bc);
                }
                #pragma unroll
                for (int fm = 0; fm < 4; ++fm)
                    #pragma unroll
                    for (int fn = 0; fn < 4; ++fn) {
                        acc[fm][fn] = __builtin_amdgcn_mfma_f32_16x16x32_bf16(
                            ah[fm], bh[fn], acc[fm][fn], 0, 0, 0);
                        acc[fm][fn] = __builtin_amdgcn_mfma_f32_16x16x32_bf16(
                            ah[fm], bl[fn], acc[fm][fn], 0, 0, 0);
                        acc[fm][fn] = __builtin_amdgcn_mfma_f32_16x16x32_bf16(
                            al[fm], bh[fn], acc[fm][fn], 0, 0, 0);
                    }
            }
        }
        // --- fold chunk into running (best, 2nd); ref dist rounding --------
        float e2v[4];
        #pragma unroll
        for (int fn = 0; fn < 4; ++fn) e2v[fn] = e2[n0 + wn * 64 + fn * 16 + col];
        #pragma unroll
        for (int fm = 0; fm < 4; ++fm)
            #pragma unroll
            for (int fn = 0; fn < 4; ++fn)
                #pragma unroll
                for (int r4 = 0; r4 < 4; ++r4) {
                    const int q = fm * 4 + r4;
                    const float dist = (z2r[q] + e2v[fn]) - 2.0f * acc[fm][fn][r4];
                    const int idx = n0 + wn * 64 + fn * 16 + col;
                    if (dist < b1[q]) { b2[q] = b1[q]; b1[q] = dist; i1[q] = idx; }
                    else if (dist < b2[q]) { b2[q] = dist; }
                }
    }

    // --- cross-thread reduction of (b1,i1,b2); slots padded to 33 ----------
    __syncthreads();
    float* Rb1 = (float*)sm;                 // [128][33]
    float* Rb2 = (float*)(sm + 16896);
    int*   Ri1 = (int*)(sm + 33792);
    const int slot = col + 16 * wn;          // 0..31
    #pragma unroll
    for (int q = 0; q < 16; ++q) {
        const int px = wm * 64 + (q >> 2) * 16 + lg * 4 + (q & 3);
        Rb1[px * 33 + slot] = b1[q];
        Rb2[px * 33 + slot] = b2[q];
        Ri1[px * 33 + slot] = i1[q];
    }
    __syncthreads();
    if (tid < BM) {
        float x1 = Rb1[tid * 33], x2 = Rb2[tid * 33]; int xi = Ri1[tid * 33];
        for (int s = 1; s < 32; ++s) {
            const float c1 = Rb1[tid * 33 + s], c2 = Rb2[tid * 33 + s];
            const int ci = Ri1[tid * 33 + s];
            const float nb2 = fminf(fmaxf(x1, c1), fminf(x2, c2));
            if (c1 < x1 || (c1 == x1 && ci < xi)) { x1 = c1; xi = ci; }
            x2 = nb2;
        }
        kwin[tid] = xi;
        const bool fl = (x2 - x1) <= MARGIN_;
        flgs[tid] = fl ? 1 : 0;
        if (fl) {
            const unsigned pos = atomicAdd(flag_cnt, 1u);
            flag_list[pos] = (unsigned)(row0 + tid);
        } else {
            out[OUT_IDX_OFF + row0 + tid] = (float)xi;
            atomicAdd(&hist[xi], 1u);
        }
    }
    __syncthreads();

    // --- epilogue for UNFLAGGED rows (exact fp32, ref rounding) ------------
    // overwrites this block's zh/zl scratch with the real z_q_st.
    float lacc = 0.0f;
    #pragma unroll 4
    for (int i = 0; i < 32; ++i) {
        const int flat4 = tid + i * 256;
        const int row = flat4 >> 6;            // wave-uniform
        if (!flgs[row]) {
            const int dj = (flat4 & 63) * 4;
            const size_t zoff = (size_t)(row0 + row) * DIM + dj;
            float4 zv = *(const float4*)(z + zoff);
            float4 ev = *(const float4*)(cb + (size_t)kwin[row] * DIM + dj);
            float dx = ev.x - zv.x, dy = ev.y - zv.y, dz = ev.z - zv.z, dw = ev.w - zv.w;
            float4 o;
            o.x = zv.x + dx; o.y = zv.y + dy; o.z = zv.z + dz; o.w = zv.w + dw;
            *(float4*)(out + zoff) = o;
            lacc += dx * dx + dy * dy + dz * dz + dw * dw;
        }
    }
    #pragma unroll
    for (int off = 32; off > 0; off >>= 1) lacc += __shfl_down(lacc, off, 64);
    if (lane == 0) wred[wid] = lacc;
    __syncthreads();
    if (tid == 0) atomicAdd(loss_sum, wred[0] + wred[1] + wred[2] + wred[3]);
}

// ---------------- repair: exact fp32 re-argmin + epilogue for flagged ------
// Bit-identical to the verified baseline's fp32 path: d-ascending fma chain,
// dist = (z2+e2[k]) - 2*dot, tie -> smaller index.
__global__ __launch_bounds__(256) void vq_fix(
    const float* __restrict__ z, const float* __restrict__ cb,
    const float* __restrict__ z2, const float* __restrict__ e2,
    const unsigned int* __restrict__ flag_cnt, const unsigned int* __restrict__ flag_list,
    unsigned int* __restrict__ hist, float* __restrict__ loss_sum,
    float* __restrict__ out)
{
    __shared__ float zrow[4][DIM];
    __shared__ float zz2[4];
    __shared__ int pxid[4];
    __shared__ float rb[4][256];
    __shared__ int   ri[4][256];
    __shared__ int   kw4[4];

    const int tid = threadIdx.x;
    const int total = (int)*flag_cnt;

    for (int base = blockIdx.x * 4; base < total; base += gridDim.x * 4) {
        const int npx = min(4, total - base);
        __syncthreads();                       // protect prev iter's shared
        if (tid < 4) {
            const int p = (int)flag_list[base + (tid < npx ? tid : 0)];
            pxid[tid] = p; zz2[tid] = z2[p];
        }
        __syncthreads();
        {
            const int q = tid >> 6, d = (tid & 63) * 4;
            float4 v = *(const float4*)(z + (size_t)pxid[q] * DIM + d);
            *(float4*)&zrow[q][d] = v;
        }
        __syncthreads();

        const int k0 = tid * 4;
        float acc[4][4];
        #pragma unroll
        for (int q = 0; q < 4; ++q)
            #pragma unroll
            for (int j = 0; j < 4; ++j) acc[q][j] = 0.0f;

        for (int d4 = 0; d4 < 64; ++d4) {
            float4 cv[4];
            #pragma unroll
            for (int j = 0; j < 4; ++j)
                cv[j] = *(const float4*)(cb + (size_t)(k0 + j) * DIM + d4 * 4);
            #pragma unroll
            for (int q = 0; q < 4; ++q) {
                float4 zv = *(const float4*)&zrow[q][d4 * 4];
                #pragma unroll
                for (int j = 0; j < 4; ++j) {
                    acc[q][j] = fmaf(zv.x, cv[j].x, acc[q][j]);
                    acc[q][j] = fmaf(zv.y, cv[j].y, acc[q][j]);
                    acc[q][j] = fmaf(zv.z, cv[j].z, acc[q][j]);
                    acc[q][j] = fmaf(zv.w, cv[j].w, acc[q][j]);
                }
            }
        }
        #pragma unroll
        for (int q = 0; q < 4; ++q) {
            float bd = FLT_MAX; int bi = 0;
            #pragma unroll
            for (int j = 0; j < 4; ++j) {       // k ascending -> strict <
                const int k = k0 + j;
                const float dist = (zz2[q] + e2[k]) - 2.0f * acc[q][j];
                if (dist < bd) { bd = dist; bi = k; }
            }
            rb[q][tid] = bd; ri[q][tid] = bi;
        }
        __syncthreads();
        {
            const int q = tid >> 6, lane = tid & 63;
            float bd = rb[q][lane]; int bi = ri[q][lane];
            #pragma unroll
            for (int s = 1; s < 4; ++s) {
                const float d2 = rb[q][lane + s * 64]; const int i2 = ri[q][lane + s * 64];
                if (d2 < bd || (d2 == bd && i2 < bi)) { bd = d2; bi = i2; }
            }
            #pragma unroll
            for (int off = 32; off > 0; off >>= 1) {
                const float d2 = __shfl_down(bd, off, 64);
                const int i2 = __shfl_down(bi, off, 64);
                if (d2 < bd || (d2 == bd && i2 < bi)) { bd = d2; bi = i2; }
            }
            if (lane == 0) kw4[q] = bi;
        }
        __syncthreads();
        {
            const int q = tid >> 6, lane = tid & 63;
            if (q < npx) {
                const int p = pxid[q];
                const int kw = kw4[q];
                const int d = lane * 4;
                float4 zv = *(const float4*)&zrow[q][d];
                float4 ev = *(const float4*)(cb + (size_t)kw * DIM + d);
                float dx = ev.x - zv.x, dy = ev.y - zv.y, dz = ev.z - zv.z, dw = ev.w - zv.w;
                float4 o;
                o.x = zv.x + dx; o.y = zv.y + dy; o.z = zv.z + dz; o.w = zv.w + dw;
                *(float4*)(out + (size_t)p * DIM + d) = o;
                float lacc = dx * dx + dy * dy + dz * dz + dw * dw;
                #pragma unroll
                for (int off = 32; off > 0; off >>= 1) lacc += __shfl_down(lacc, off, 64);
                if (lane == 0) {
                    atomicAdd(loss_sum, lacc);
                    out[OUT_IDX_OFF + p] = (float)kw;
                    atomicAdd(&hist[kw], 1u);
                }
            }
        }
    }
}

// ---------------- finalize: losses + perplexity -----------------------------
__global__ __launch_bounds__(1024) void vq_finalize(
    const unsigned int* __restrict__ hist, const float* __restrict__ loss_sum,
    float* __restrict__ out)
{
    __shared__ float sred[16];
    __shared__ float totalsh;
    const int tid = threadIdx.x;
    const float c = (float)hist[tid];

    float t = c;
    #pragma unroll
    for (int off = 32; off > 0; off >>= 1) t += __shfl_down(t, off, 64);
    if ((tid & 63) == 0) sred[tid >> 6] = t;
    __syncthreads();
    if (tid == 0) {
        float s = 0.0f;
        for (int i = 0; i < 16; ++i) s += sred[i];
        totalsh = s;
    }
    __syncthreads();
    const float total = totalsh;
    const float prob = c / (total + EPS_);
    float term = prob * logf(prob + EPS_);
    __syncthreads();   // all phase-1 reads of sred done
    #pragma unroll
    for (int off = 32; off > 0; off >>= 1) term += __shfl_down(term, off, 64);
    if ((tid & 63) == 0) sred[tid >> 6] = term;
    __syncthreads();
    if (tid == 0) {
        float s = 0.0f;
        for (int i = 0; i < 16; ++i) s += sred[i];
        const float perp = expf(-s);
        const float S = *loss_sum;
        const float mean = S / (float)(P_TOT * DIM);
        out[OUT_LOSS_OFF + 0] = mean;                  // commitment_loss
        out[OUT_LOSS_OFF + 1] = mean;                  // codebook_loss
        out[OUT_LOSS_OFF + 2] = mean + BETA_ * mean;   // cluster_loss
        out[OUT_LOSS_OFF + 3] = perp;                  // perplexity
    }
}

extern "C" void kernel_launch(void* const* d_in, const int* in_sizes, int n_in,
                              void* d_out, int out_size, void* d_ws, size_t ws_size,
                              hipStream_t stream) {
    const float* z  = (const float*)d_in[0];
    const float* cb = (const float*)d_in[1];
    float* out = (float*)d_out;

    // ws: z2[P] | e2[K] | hist[K] | loss_sum | flag_cnt | flag_list[P] |
    //     cbh[K*D] bf16 | cbl[K*D] bf16   (~1.9 MiB)
    float* z2 = (float*)d_ws;
    float* e2 = z2 + P_TOT;
    unsigned int* hist = (unsigned int*)(e2 + KTOT);
    float* loss_sum = (float*)(hist + KTOT);
    unsigned int* flag_cnt = (unsigned int*)(loss_sum + 1);
    unsigned int* flag_list = flag_cnt + 1;
    unsigned short* cbh = (unsigned short*)(((uintptr_t)(flag_list + P_TOT) + 15) & ~(uintptr_t)15);
    unsigned short* cbl = cbh + (size_t)KTOT * DIM;

    vq_pre<<<P_TOT / 4 + KTOT / 4, 256, 0, stream>>>(z, cb, z2, e2, cbh, cbl,
                                                     hist, loss_sum, flag_cnt, out);
    vq_argmin<<<P_TOT / BM, 256, 0, stream>>>(z, cb, cbh, cbl, z2, e2,
                                              hist, loss_sum, flag_cnt, flag_list, out);
    vq_fix<<<1024, 256, 0, stream>>>(z, cb, z2, e2, flag_cnt, flag_list,
                                     hist, loss_sum, out);
    vq_finalize<<<1, 1024, 0, stream>>>(hist, loss_sum, out);
}

// Round 9
// 340.468 us; speedup vs baseline: 1.3313x; 1.1384x over previous
//
#include <hip/hip_runtime.h>
#include <cfloat>
#include <math.h>

// Problem constants (z: [16,64,64,256] fp32, codebook: [1024,256] fp32)
#define P_TOT 65536
#define DIM   256
#define KTOT  1024
#define BETA_ 0.25f
#define EPS_  1e-5f
// flag threshold: >= 2*(2*delta_ze) + 2*ULP(dist) with worst-case
// delta_ze <= ~8e-6 (3-term bf16 split + ref fp32 err) and ULP <= 3.05e-5.
#define MARGIN_ 1.5e-4f

// d_out layout (float32, concatenated in reference return order):
// [0, P*D) z_q_st | [P*D+0..3] losses+perplexity | [P*D+4, +P) indices
// vq_pre temporarily stores zh/zl bf16 (512B+512B per row) in the z_q_st
// region; each argmin block consumes only its own 128 rows before
// overwriting them with the real z_q_st (flagged rows finished by vq_fix).
#define OUT_LOSS_OFF ((size_t)P_TOT * DIM)
#define OUT_IDX_OFF  (OUT_LOSS_OFF + 4)

typedef __attribute__((ext_vector_type(8))) short s16x8;   // 8 bf16 (4 VGPRs)
typedef __attribute__((ext_vector_type(4))) float f32x4;   // MFMA acc

__device__ __forceinline__ unsigned short f2bf(float x) {  // RNE f32->bf16
    unsigned u = __float_as_uint(x);
    u += 0x7FFFu + ((u >> 16) & 1u);
    return (unsigned short)(u >> 16);
}
__device__ __forceinline__ float bf2f(unsigned short h) {
    return __uint_as_float(((unsigned)h) << 16);
}
// async global->LDS direct copy, 16B per lane; lds ptr MUST be wave-uniform.
__device__ __forceinline__ void gl16(const void* g, void* l) {
    __builtin_amdgcn_global_load_lds(
        (const __attribute__((address_space(1))) unsigned int*)g,
        (__attribute__((address_space(3))) unsigned int*)l, 16, 0, 0);
}

// ------- fused pre-pass: zsplit (blocks < P/4) + codebook prep (rest) -------
// z part:  z2[p] = sum(z[p]^2); out row p: [512B zh | 512B zl]
// cb part: e2[k]; cbh row k (512B), cbl row k (512B); zero hist/loss/flags
__global__ __launch_bounds__(256) void vq_pre(
    const float* __restrict__ z, const float* __restrict__ cb,
    float* __restrict__ z2, float* __restrict__ e2,
    unsigned short* __restrict__ cbh, unsigned short* __restrict__ cbl,
    unsigned int* __restrict__ hist,
    float* __restrict__ loss_sum, unsigned int* __restrict__ flag_cnt,
    float* __restrict__ out)
{
    const int tid = threadIdx.x;
    const int lane = tid & 63;
    const int wave = tid >> 6;
    const int bid = blockIdx.x;

    if (bid < P_TOT / 4) {
        const int p = bid * 4 + wave;
        float4 v = *(const float4*)(z + (size_t)p * DIM + lane * 4);
        float s = v.x * v.x + v.y * v.y + v.z * v.z + v.w * v.w;
        #pragma unroll
        for (int off = 32; off > 0; off >>= 1) s += __shfl_down(s, off, 64);
        if (lane == 0) z2[p] = s;

        unsigned short h0 = f2bf(v.x), h1 = f2bf(v.y), h2 = f2bf(v.z), h3 = f2bf(v.w);
        unsigned short l0 = f2bf(v.x - bf2f(h0)), l1 = f2bf(v.y - bf2f(h1));
        unsigned short l2 = f2bf(v.z - bf2f(h2)), l3 = f2bf(v.w - bf2f(h3));
        uint2 hp, lp;
        hp.x = (unsigned)h0 | ((unsigned)h1 << 16); hp.y = (unsigned)h2 | ((unsigned)h3 << 16);
        lp.x = (unsigned)l0 | ((unsigned)l1 << 16); lp.y = (unsigned)l2 | ((unsigned)l3 << 16);
        char* rowb = (char*)out + (size_t)p * 1024;
        *(uint2*)(rowb + lane * 8) = hp;
        *(uint2*)(rowb + 512 + lane * 8) = lp;
    } else {
        const int rel = bid - P_TOT / 4;
        const int k = rel * 4 + wave;
        float4 v = *(const float4*)(cb + (size_t)k * DIM + lane * 4);
        float s = v.x * v.x + v.y * v.y + v.z * v.z + v.w * v.w;
        #pragma unroll
        for (int off = 32; off > 0; off >>= 1) s += __shfl_down(s, off, 64);
        if (lane == 0) e2[k] = s;

        unsigned short h0 = f2bf(v.x), h1 = f2bf(v.y), h2 = f2bf(v.z), h3 = f2bf(v.w);
        unsigned short l0 = f2bf(v.x - bf2f(h0)), l1 = f2bf(v.y - bf2f(h1));
        unsigned short l2 = f2bf(v.z - bf2f(h2)), l3 = f2bf(v.w - bf2f(h3));
        uint2 hp, lp;
        hp.x = (unsigned)h0 | ((unsigned)h1 << 16); hp.y = (unsigned)h2 | ((unsigned)h3 << 16);
        lp.x = (unsigned)l0 | ((unsigned)l1 << 16); lp.y = (unsigned)l2 | ((unsigned)l3 << 16);
        *(uint2*)(cbh + (size_t)k * DIM + lane * 4) = hp;
        *(uint2*)(cbl + (size_t)k * DIM + lane * 4) = lp;

        if (rel < 4) hist[rel * 256 + tid] = 0u;
        if (rel == 4 && tid == 0) { *loss_sum = 0.0f; *flag_cnt = 0u; }
    }
}

// ---------------- main: bf16x2 split MFMA GEMM-argmin + margin flag ---------
// Round-2/8 verified structure (argmin ~155us, MfmaUtil 28): 256 thr, 2x2
// waves, BM=BN=128, BK=64, single-buffered LDS, 2 barriers/step. Rounds 3-7
// perturbations (2-phase dbuf, BK=32, 8-wave, launch_bounds 4) ALL
// regressed -- this serial structure + 2 desynced blocks/CU (implicit m114
// wave overlap) is the empirical optimum for this shape.
// This round adds ONLY T5 s_setprio(1) around the MFMA cluster: with two
// desynced blocks per CU, staging-phase and MFMA-phase waves coexist, the
// regime where setprio pays (m191); null in lockstep GEMM (m190) = no harm.
// Staging is pure global_load_lds: XOR-16B swizzle applied on the per-lane
// GLOBAL source address, LDS dest linear (rule #21).
#define BM 128
#define BN 128

__global__ __launch_bounds__(256, 2) void vq_argmin(
    const float* __restrict__ z, const float* __restrict__ cb,
    const unsigned short* __restrict__ cbh, const unsigned short* __restrict__ cbl,
    const float* __restrict__ z2, const float* __restrict__ e2,
    unsigned int* __restrict__ hist, float* __restrict__ loss_sum,
    unsigned int* __restrict__ flag_cnt, unsigned int* __restrict__ flag_list,
    float* __restrict__ out)
{
    // LDS: 4 bf16 tiles [128 rows][128B] (Ah,Al,Bh,Bl) = 64KB, reused as red.
    __shared__ __align__(16) char sm[65536];
    __shared__ int kwin[BM];
    __shared__ unsigned char flgs[BM];
    __shared__ float wred[4];

    const int tid = threadIdx.x;
    const int lane = tid & 63;
    const int wid = tid >> 6;
    const int wm = wid >> 1, wn = wid & 1;
    const int col = lane & 15;      // frag column
    const int lg  = lane >> 4;      // k-group
    const int swz = lane & 7;
    const int row0 = blockIdx.x * BM;

    const char* zsB  = (const char*)out;       // zh/zl packed rows (1KB/row)
    const char* cbhB = (const char*)cbh;       // 512B/row
    const char* cblB = (const char*)cbl;

    // persistent per-thread state: 16 pixels x (best, 2nd-best, idx)
    float b1[16], b2[16]; int i1[16];
    float z2r[16];
    #pragma unroll
    for (int q = 0; q < 16; ++q) {
        b1[q] = FLT_MAX; b2[q] = FLT_MAX; i1[q] = 0;
        z2r[q] = z2[row0 + wm * 64 + (q >> 2) * 16 + lg * 4 + (q & 3)];
    }

    int aRow[4], bRow[4];
    #pragma unroll
    for (int f = 0; f < 4; ++f) {
        aRow[f] = (wm * 64 + f * 16 + col) * 128;   // byte base of LDS row
        bRow[f] = (wn * 64 + f * 16 + col) * 128;
    }
    const int bc0 = ((0 + lg) ^ swz) << 4;          // swizzled 16B col, ks=0
    const int bc1 = ((4 + lg) ^ swz) << 4;          // ks=1

    const int sr  = lane >> 3;                      // staging sub-row 0..7
    const int scb = lane & 7;                       // staging phys 16B block

    #pragma unroll 1
    for (int nc = 0; nc < KTOT / BN; ++nc) {
        const int n0 = nc * BN;
        f32x4 acc[4][4];
        #pragma unroll
        for (int fm = 0; fm < 4; ++fm)
            #pragma unroll
            for (int fn = 0; fn < 4; ++fn)
                acc[fm][fn] = (f32x4){0.0f, 0.0f, 0.0f, 0.0f};

        #pragma unroll 1
        for (int kc = 0; kc < 4; ++kc) {            // BK=64
            __syncthreads();
            // --- stage: 16 x global_load_lds (4 tiles x 4 row-slabs) -------
            #pragma unroll
            for (int i = 0; i < 4; ++i) {
                const int rloc = wid * 32 + i * 8 + sr;           // 0..127
                const int cb16 = ((scb ^ (rloc & 7)) << 4);       // src block
                const size_t aoff = ((size_t)(row0 + rloc) << 10) + (kc << 7);
                const size_t boff = ((size_t)(n0 + rloc) << 9) + (kc << 7);
                char* lb = sm + (wid * 32 + i * 8) * 128;         // uniform
                gl16(zsB + aoff + cb16,        lb);               // Ah @ 0
                gl16(zsB + aoff + 512 + cb16,  lb + 16384);       // Al @ 16K
                gl16(cbhB + boff + cb16,       lb + 32768);       // Bh @ 32K
                gl16(cblB + boff + cb16,       lb + 49152);       // Bl @ 48K
            }
            __syncthreads();   // drains vmcnt -> tiles visible
            // --- MFMA: 3-term bf16x2 split into shared f32 accumulator ----
            #pragma unroll
            for (int ks = 0; ks < 2; ++ks) {
                const int bc = ks ? bc1 : bc0;
                s16x8 ah[4], al[4], bh[4], bl[4];
                #pragma unroll
                for (int f = 0; f < 4; ++f) {
                    ah[f] = *(const s16x8*)(sm + aRow[f] + bc);
                    al[f] = *(const s16x8*)(sm + 16384 + aRow[f] + bc);
                    bh[f] = *(const s16x8*)(sm + 32768 + bRow[f] + bc);
                    bl[f] = *(const s16x8*)(sm + 49152 + bRow[f] + bc);
                }
                __builtin_amdgcn_s_setprio(1);     // T5: favor MFMA waves
                #pragma unroll
                for (int fm = 0; fm < 4; ++fm)
                    #pragma unroll
                    for (int fn = 0; fn < 4; ++fn) {
                        acc[fm][fn] = __builtin_amdgcn_mfma_f32_16x16x32_bf16(
                            ah[fm], bh[fn], acc[fm][fn], 0, 0, 0);
                        acc[fm][fn] = __builtin_amdgcn_mfma_f32_16x16x32_bf16(
                            ah[fm], bl[fn], acc[fm][fn], 0, 0, 0);
                        acc[fm][fn] = __builtin_amdgcn_mfma_f32_16x16x32_bf16(
                            al[fm], bh[fn], acc[fm][fn], 0, 0, 0);
                    }
                __builtin_amdgcn_s_setprio(0);
            }
        }
        // --- fold chunk into running (best, 2nd); ref dist rounding --------
        float e2v[4];
        #pragma unroll
        for (int fn = 0; fn < 4; ++fn) e2v[fn] = e2[n0 + wn * 64 + fn * 16 + col];
        #pragma unroll
        for (int fm = 0; fm < 4; ++fm)
            #pragma unroll
            for (int fn = 0; fn < 4; ++fn)
                #pragma unroll
                for (int r4 = 0; r4 < 4; ++r4) {
                    const int q = fm * 4 + r4;
                    const float dist = (z2r[q] + e2v[fn]) - 2.0f * acc[fm][fn][r4];
                    const int idx = n0 + wn * 64 + fn * 16 + col;
                    if (dist < b1[q]) { b2[q] = b1[q]; b1[q] = dist; i1[q] = idx; }
                    else if (dist < b2[q]) { b2[q] = dist; }
                }
    }

    // --- cross-thread reduction of (b1,i1,b2); slots padded to 33 ----------
    __syncthreads();
    float* Rb1 = (float*)sm;                 // [128][33]
    float* Rb2 = (float*)(sm + 16896);
    int*   Ri1 = (int*)(sm + 33792);
    const int slot = col + 16 * wn;          // 0..31
    #pragma unroll
    for (int q = 0; q < 16; ++q) {
        const int px = wm * 64 + (q >> 2) * 16 + lg * 4 + (q & 3);
        Rb1[px * 33 + slot] = b1[q];
        Rb2[px * 33 + slot] = b2[q];
        Ri1[px * 33 + slot] = i1[q];
    }
    __syncthreads();
    if (tid < BM) {
        float x1 = Rb1[tid * 33], x2 = Rb2[tid * 33]; int xi = Ri1[tid * 33];
        for (int s = 1; s < 32; ++s) {
            const float c1 = Rb1[tid * 33 + s], c2 = Rb2[tid * 33 + s];
            const int ci = Ri1[tid * 33 + s];
            const float nb2 = fminf(fmaxf(x1, c1), fminf(x2, c2));
            if (c1 < x1 || (c1 == x1 && ci < xi)) { x1 = c1; xi = ci; }
            x2 = nb2;
        }
        kwin[tid] = xi;
        const bool fl = (x2 - x1) <= MARGIN_;
        flgs[tid] = fl ? 1 : 0;
        if (fl) {
            const unsigned pos = atomicAdd(flag_cnt, 1u);
            flag_list[pos] = (unsigned)(row0 + tid);
        } else {
            out[OUT_IDX_OFF + row0 + tid] = (float)xi;
            atomicAdd(&hist[xi], 1u);
        }
    }
    __syncthreads();

    // --- epilogue for UNFLAGGED rows (exact fp32, ref rounding) ------------
    // overwrites this block's zh/zl scratch with the real z_q_st.
    float lacc = 0.0f;
    #pragma unroll 4
    for (int i = 0; i < 32; ++i) {
        const int flat4 = tid + i * 256;
        const int row = flat4 >> 6;            // wave-uniform
        if (!flgs[row]) {
            const int dj = (flat4 & 63) * 4;
            const size_t zoff = (size_t)(row0 + row) * DIM + dj;
            float4 zv = *(const float4*)(z + zoff);
            float4 ev = *(const float4*)(cb + (size_t)kwin[row] * DIM + dj);
            float dx = ev.x - zv.x, dy = ev.y - zv.y, dz = ev.z - zv.z, dw = ev.w - zv.w;
            float4 o;
            o.x = zv.x + dx; o.y = zv.y + dy; o.z = zv.z + dz; o.w = zv.w + dw;
            *(float4*)(out + zoff) = o;
            lacc += dx * dx + dy * dy + dz * dz + dw * dw;
        }
    }
    #pragma unroll
    for (int off = 32; off > 0; off >>= 1) lacc += __shfl_down(lacc, off, 64);
    if (lane == 0) wred[wid] = lacc;
    __syncthreads();
    if (tid == 0) atomicAdd(loss_sum, wred[0] + wred[1] + wred[2] + wred[3]);
}

// ---------------- repair: exact fp32 re-argmin + epilogue for flagged ------
// Bit-identical to the verified baseline's fp32 path: d-ascending fma chain,
// dist = (z2+e2[k]) - 2*dot, tie -> smaller index. 8 px per block-iteration
// (was 4): halves codebook re-reads and iteration count at ~equal latency.
#define FPX 8
__global__ __launch_bounds__(256) void vq_fix(
    const float* __restrict__ z, const float* __restrict__ cb,
    const float* __restrict__ z2, const float* __restrict__ e2,
    const unsigned int* __restrict__ flag_cnt, const unsigned int* __restrict__ flag_list,
    unsigned int* __restrict__ hist, float* __restrict__ loss_sum,
    float* __restrict__ out)
{
    __shared__ float zrow[FPX][DIM];
    __shared__ float zz2[FPX];
    __shared__ int pxid[FPX];
    __shared__ float rb[FPX][256];
    __shared__ int   ri[FPX][256];
    __shared__ int   kw8[FPX];

    const int tid = threadIdx.x;
    const int wave = tid >> 6;
    const int lane = tid & 63;
    const int total = (int)*flag_cnt;

    for (int base = blockIdx.x * FPX; base < total; base += gridDim.x * FPX) {
        const int npx = min(FPX, total - base);
        __syncthreads();                       // protect prev iter's shared
        if (tid < FPX) {
            const int p = (int)flag_list[base + (tid < npx ? tid : 0)];
            pxid[tid] = p; zz2[tid] = z2[p];
        }
        __syncthreads();
        #pragma unroll
        for (int r = wave; r < FPX; r += 4) {
            const int d = lane * 4;
            float4 v = *(const float4*)(z + (size_t)pxid[r] * DIM + d);
            *(float4*)&zrow[r][d] = v;
        }
        __syncthreads();

        const int k0 = tid * 4;
        float acc[FPX][4];
        #pragma unroll
        for (int q = 0; q < FPX; ++q)
            #pragma unroll
            for (int j = 0; j < 4; ++j) acc[q][j] = 0.0f;

        for (int d4 = 0; d4 < 64; ++d4) {
            float4 cv[4];
            #pragma unroll
            for (int j = 0; j < 4; ++j)
                cv[j] = *(const float4*)(cb + (size_t)(k0 + j) * DIM + d4 * 4);
            #pragma unroll
            for (int q = 0; q < FPX; ++q) {
                float4 zv = *(const float4*)&zrow[q][d4 * 4];
                #pragma unroll
                for (int j = 0; j < 4; ++j) {
                    acc[q][j] = fmaf(zv.x, cv[j].x, acc[q][j]);
                    acc[q][j] = fmaf(zv.y, cv[j].y, acc[q][j]);
                    acc[q][j] = fmaf(zv.z, cv[j].z, acc[q][j]);
                    acc[q][j] = fmaf(zv.w, cv[j].w, acc[q][j]);
                }
            }
        }
        #pragma unroll
        for (int q = 0; q < FPX; ++q) {
            float bd = FLT_MAX; int bi = 0;
            #pragma unroll
            for (int j = 0; j < 4; ++j) {       // k ascending -> strict <
                const int k = k0 + j;
                const float dist = (zz2[q] + e2[k]) - 2.0f * acc[q][j];
                if (dist < bd) { bd = dist; bi = k; }
            }
            rb[q][tid] = bd; ri[q][tid] = bi;
        }
        __syncthreads();
        #pragma unroll
        for (int rq = wave; rq < FPX; rq += 4) {
            float bd = rb[rq][lane]; int bi = ri[rq][lane];
            #pragma unroll
            for (int s = 1; s < 4; ++s) {
                const float d2 = rb[rq][lane + s * 64]; const int i2 = ri[rq][lane + s * 64];
                if (d2 < bd || (d2 == bd && i2 < bi)) { bd = d2; bi = i2; }
            }
            #pragma unroll
            for (int off = 32; off > 0; off >>= 1) {
                const float d2 = __shfl_down(bd, off, 64);
                const int i2 = __shfl_down(bi, off, 64);
                if (d2 < bd || (d2 == bd && i2 < bi)) { bd = d2; bi = i2; }
            }
            if (lane == 0) kw8[rq] = bi;
        }
        __syncthreads();
        #pragma unroll
        for (int rq = wave; rq < FPX; rq += 4) {
            if (rq < npx) {
                const int p = pxid[rq];
                const int kw = kw8[rq];
                const int d = lane * 4;
                float4 zv = *(const float4*)&zrow[rq][d];
                float4 ev = *(const float4*)(cb + (size_t)kw * DIM + d);
                float dx = ev.x - zv.x, dy = ev.y - zv.y, dz = ev.z - zv.z, dw = ev.w - zv.w;
                float4 o;
                o.x = zv.x + dx; o.y = zv.y + dy; o.z = zv.z + dz; o.w = zv.w + dw;
                *(float4*)(out + (size_t)p * DIM + d) = o;
                float lacc = dx * dx + dy * dy + dz * dz + dw * dw;
                #pragma unroll
                for (int off = 32; off > 0; off >>= 1) lacc += __shfl_down(lacc, off, 64);
                if (lane == 0) {
                    atomicAdd(loss_sum, lacc);
                    out[OUT_IDX_OFF + p] = (float)kw;
                    atomicAdd(&hist[kw], 1u);
                }
            }
        }
    }
}

// ---------------- finalize: losses + perplexity -----------------------------
__global__ __launch_bounds__(1024) void vq_finalize(
    const unsigned int* __restrict__ hist, const float* __restrict__ loss_sum,
    float* __restrict__ out)
{
    __shared__ float sred[16];
    __shared__ float totalsh;
    const int tid = threadIdx.x;
    const float c = (float)hist[tid];

    float t = c;
    #pragma unroll
    for (int off = 32; off > 0; off >>= 1) t += __shfl_down(t, off, 64);
    if ((tid & 63) == 0) sred[tid >> 6] = t;
    __syncthreads();
    if (tid == 0) {
        float s = 0.0f;
        for (int i = 0; i < 16; ++i) s += sred[i];
        totalsh = s;
    }
    __syncthreads();
    const float total = totalsh;
    const float prob = c / (total + EPS_);
    float term = prob * logf(prob + EPS_);
    __syncthreads();   // all phase-1 reads of sred done
    #pragma unroll
    for (int off = 32; off > 0; off >>= 1) term += __shfl_down(term, off, 64);
    if ((tid & 63) == 0) sred[tid >> 6] = term;
    __syncthreads();
    if (tid == 0) {
        float s = 0.0f;
        for (int i = 0; i < 16; ++i) s += sred[i];
        const float perp = expf(-s);
        const float S = *loss_sum;
        const float mean = S / (float)(P_TOT * DIM);
        out[OUT_LOSS_OFF + 0] = mean;                  // commitment_loss
        out[OUT_LOSS_OFF + 1] = mean;                  // codebook_loss
        out[OUT_LOSS_OFF + 2] = mean + BETA_ * mean;   // cluster_loss
        out[OUT_LOSS_OFF + 3] = perp;                  // perplexity
    }
}

extern "C" void kernel_launch(void* const* d_in, const int* in_sizes, int n_in,
                              void* d_out, int out_size, void* d_ws, size_t ws_size,
                              hipStream_t stream) {
    const float* z  = (const float*)d_in[0];
    const float* cb = (const float*)d_in[1];
    float* out = (float*)d_out;

    // ws: z2[P] | e2[K] | hist[K] | loss_sum | flag_cnt | flag_list[P] |
    //     cbh[K*D] bf16 | cbl[K*D] bf16   (~1.9 MiB)
    float* z2 = (float*)d_ws;
    float* e2 = z2 + P_TOT;
    unsigned int* hist = (unsigned int*)(e2 + KTOT);
    float* loss_sum = (float*)(hist + KTOT);
    unsigned int* flag_cnt = (unsigned int*)(loss_sum + 1);
    unsigned int* flag_list = flag_cnt + 1;
    unsigned short* cbh = (unsigned short*)(((uintptr_t)(flag_list + P_TOT) + 15) & ~(uintptr_t)15);
    unsigned short* cbl = cbh + (size_t)KTOT * DIM;

    vq_pre<<<P_TOT / 4 + KTOT / 4, 256, 0, stream>>>(z, cb, z2, e2, cbh, cbl,
                                                     hist, loss_sum, flag_cnt, out);
    vq_argmin<<<P_TOT / BM, 256, 0, stream>>>(z, cb, cbh, cbl, z2, e2,
                                              hist, loss_sum, flag_cnt, flag_list, out);
    vq_fix<<<1024, 256, 0, stream>>>(z, cb, z2, e2, flag_cnt, flag_list,
                                     hist, loss_sum, out);
    vq_finalize<<<1, 1024, 0, stream>>>(hist, loss_sum, out);
}